// Round 1
// baseline (208.815 us; speedup 1.0000x reference)
//
#include <hip/hip_runtime.h>
#include <stdint.h>

#define BB 8
#define CC 8
#define HH 512
#define WW 512
#define HWSZ (HH * WW)

typedef float v4 __attribute__((ext_vector_type(4)));

#define LOG2_CLAMP -144.26950409f   // -100 / ln2

__device__ __forceinline__ v4 uload4(const float* __restrict__ p) {
    v4 r;
    __builtin_memcpy(&r, p, sizeof(v4));   // 4B-aligned dwordx4
    return r;
}
__device__ __forceinline__ v4 aload4(const float* __restrict__ p) {
    return *(const v4* __restrict__)p;
}

__device__ __forceinline__ v4 sig4(v4 x) {
    v4 r;
#pragma unroll
    for (int i = 0; i < 4; ++i)
        r[i] = __builtin_amdgcn_rcpf(1.0f + __expf(-x[i]));
    return r;
}

// async global->LDS: 16B per lane, dest = wave-uniform base + lane*16
__device__ __forceinline__ void gload_lds16(const float* g, float* l) {
    __builtin_amdgcn_global_load_lds(
        (const __attribute__((address_space(1))) void*)g,
        (__attribute__((address_space(3))) void*)l, 16, 0, 0);
}

__global__ __launch_bounds__(256, 4) void bicon_loss_kernel(
    const float* __restrict__ atts, const float* __restrict__ dets,
    const float* __restrict__ target, const float* __restrict__ con,
    float* __restrict__ out)
{
    // atts-neighbor staging: [vote k][wave][lane*4] = 32 KiB -> 4 blocks/CU
    __shared__ __align__(16) float an_lds[8][4][256];

    // XCD-chunked swizzle: XCD x = bid%8 gets a contiguous row range so that
    // halo re-reads (row r-1 / r+2) hit the local XCD L2. 2048 % 8 == 0 -> bijective.
    const int nchunk = (int)gridDim.x >> 3;
    const int bid = ((int)blockIdx.x & 7) * nchunk + ((int)blockIdx.x >> 3);

    const int tid  = (int)threadIdx.x;
    const int idx  = bid * 256 + tid;                // 4-pixel group
    const int w0   = (idx & 127) << 2;
    const int row  = idx >> 7;                       // b*H + h
    const int h    = row & (HH - 1);
    const int b    = row >> 9;
    const int lane = tid & 63;
    const int wid  = tid >> 6;

    const int hm = (h > 0) ? h - 1 : 0;
    const int hp = (h < HH - 1) ? h + 1 : HH - 1;
    const float mh0 = (h > 0) ? 1.0f : 0.0f;
    const float mh1 = (h < HH - 1) ? 1.0f : 0.0f;
    const float mw0 = (w0 == 0) ? 0.0f : 1.0f;
    const float mw3 = (w0 == WW - 4) ? 0.0f : 1.0f;

    const int offC = h * WW + w0;
    const int offU = hm * WW + w0;
    const int offD = hp * WW + w0;

    const float* __restrict__ ab = atts + b * CC * HWSZ;
    const float* __restrict__ db = dets + b * CC * HWSZ;
    const float* __restrict__ cb = con  + b * CC * HWSZ;

    // ---- phase 0: atts-neighbor loads straight to LDS (zero VGPR cost MLP) ----
    gload_lds16(ab + 7 * HWSZ + offU - 1, &an_lds[0][wid][0]);
    gload_lds16(ab + 6 * HWSZ + offU    , &an_lds[1][wid][0]);
    gload_lds16(ab + 5 * HWSZ + offU + 1, &an_lds[2][wid][0]);
    gload_lds16(ab + 4 * HWSZ + offC - 1, &an_lds[3][wid][0]);
    gload_lds16(ab + 3 * HWSZ + offC + 1, &an_lds[4][wid][0]);
    gload_lds16(ab + 2 * HWSZ + offD - 1, &an_lds[5][wid][0]);
    gload_lds16(ab + 1 * HWSZ + offD    , &an_lds[6][wid][0]);
    gload_lds16(ab + 0 * HWSZ + offD + 1, &an_lds[7][wid][0]);

    // ---- phase 1: register loads (dets first: consumed first) ----
    v4 dc[8], dn[8], ac[8];
#pragma unroll
    for (int c = 0; c < 8; ++c) dc[c] = aload4(db + c * HWSZ + offC);
    dn[0] = uload4(db + 7 * HWSZ + offU - 1);
    dn[1] = aload4(db + 6 * HWSZ + offU);
    dn[2] = uload4(db + 5 * HWSZ + offU + 1);
    dn[3] = uload4(db + 4 * HWSZ + offC - 1);
    dn[4] = uload4(db + 3 * HWSZ + offC + 1);
    dn[5] = uload4(db + 2 * HWSZ + offD - 1);
    dn[6] = aload4(db + 1 * HWSZ + offD);
    dn[7] = uload4(db + 0 * HWSZ + offD + 1);
#pragma unroll
    for (int c = 0; c < 8; ++c) ac[c] = aload4(ab + c * HWSZ + offC);

    // con/target -> selector bitmasks (exact: values are 0.0/1.0), frees ~36 VGPRs
    uint32_t sel = 0u;
#pragma unroll
    for (int c = 0; c < 8; ++c) {
        v4 cvv = aload4(cb + c * HWSZ + offC);
#pragma unroll
        for (int i = 0; i < 4; ++i)
            if (cvv[i] > 0.5f) sel |= (1u << (c * 4 + i));
    }
    v4 tv = aload4(target + b * HWSZ + offC);
    uint32_t tb = 0u;
#pragma unroll
    for (int i = 0; i < 4; ++i)
        if (tv[i] > 0.5f) tb |= (1u << i);

    // border mask factors per vote k: {elem0, elems1-2, elem3}; replaces mk[8] v4s
    const float mkA[8] = {mh0 * mw0, mh0, mh0,       mw0, 1.f, mh1 * mw0, mh1, mh1};
    const float mkB[8] = {mh0,       mh0, mh0,       1.f, 1.f, mh1,       mh1, mh1};
    const float mkC[8] = {mh0,       mh0, mh0 * mw3, 1.f, mw3, mh1,       mh1, mh1 * mw3};

    const v4 one = {1.f, 1.f, 1.f, 1.f};

    // ================= dets branch (neighbors from registers) =================
    v4 pb0 = one, pb1 = one, pc = one;
    v4 vsum = {0.f, 0.f, 0.f, 0.f};
    v4 vmin = {1e30f, 1e30f, 1e30f, 1e30f};
#pragma unroll
    for (int k = 0; k < 8; ++k) {
        v4 s = sig4(dc[k]);
        v4 n = sig4(dn[k]);
        n[0] *= mkA[k]; n[1] *= mkB[k]; n[2] *= mkB[k]; n[3] *= mkC[k];
        v4 v = s * n;
        vsum += v;
        vmin = __builtin_elementwise_min(vmin, v);
        v4 av, as;
#pragma unroll
        for (int i = 0; i < 4; ++i) {
            const bool bt = (sel >> (k * 4 + i)) & 1u;
            av[i] = bt ? v[i] : 1.0f - v[i];
            as[i] = bt ? s[i] : 1.0f - s[i];
        }
        if (k < 4) pb0 *= av; else pb1 *= av;
        pc *= as;
    }
    const v4 glo2  = vsum * 0.125f;
    const v4 vmin2 = vmin;
    float Lb2 = 0.f, Lc2 = 0.f;
#pragma unroll
    for (int i = 0; i < 4; ++i) {
        Lb2 += fmaxf(__log2f(pb0[i]), LOG2_CLAMP) + fmaxf(__log2f(pb1[i]), LOG2_CLAMP);
        Lc2 += fmaxf(__log2f(pc[i]), LOG2_CLAMP);
    }

    // drain all outstanding vmem (incl. LDS-staged atts neighbors); own-wave data,
    // so vmcnt suffices — no barrier needed.
    asm volatile("s_waitcnt vmcnt(0)" ::: "memory");

    // ================= atts branch (neighbors from LDS) =================
    v4 qb0 = one, qb1 = one, qc = one;
    v4 qsum = {0.f, 0.f, 0.f, 0.f};
#pragma unroll
    for (int k = 0; k < 8; ++k) {
        v4 s = sig4(ac[k]);
        v4 n = sig4(*(const v4*)&an_lds[k][wid][lane * 4]);   // ds_read_b128
        n[0] *= mkA[k]; n[1] *= mkB[k]; n[2] *= mkB[k]; n[3] *= mkC[k];
        v4 v = s * n;
        qsum += v;
        v4 av, as;
#pragma unroll
        for (int i = 0; i < 4; ++i) {
            const bool bt = (sel >> (k * 4 + i)) & 1u;
            av[i] = bt ? v[i] : 1.0f - v[i];
            as[i] = bt ? s[i] : 1.0f - s[i];
        }
        if (k < 4) qb0 *= av; else qb1 *= av;
        qc *= as;
    }
    const v4 glo1 = qsum * 0.125f;
    float Lb1 = 0.f, Lc1 = 0.f;
#pragma unroll
    for (int i = 0; i < 4; ++i) {
        Lb1 += fmaxf(__log2f(qb0[i]), LOG2_CLAMP) + fmaxf(__log2f(qb1[i]), LOG2_CLAMP);
        Lc1 += fmaxf(__log2f(qc[i]), LOG2_CLAMP);
    }

    // ============ pixel-level: bce(glo1,t) + bce(dec,t), combined log ============
    float Lp = 0.f;
#pragma unroll
    for (int i = 0; i < 4; ++i) {
        const uint32_t mI    = 0x11111111u << i;
        const uint32_t bitsI = sel & mI;
        const bool edge = (bitsI != 0u) && (bitsI != mI);   // 0 < popcount < 8
        const float dec = edge ? (1.0f - vmin2[i]) : glo2[i];
        const bool  ti  = (tb >> i) & 1u;
        const float a   = ti ? glo1[i] : 1.0f - glo1[i];
        const float bs  = ti ? dec     : 1.0f - dec;
        Lp += fmaxf(__log2f(a * bs), LOG2_CLAMP);
    }

    const float wbic = 0.2f / (float)(BB * CC * HWSZ);
    const float wcon = 0.8f / (float)(BB * CC * HWSZ);
    const float wpix = 1.0f / (float)(BB * HWSZ);
    const float ln2  = 0.69314718056f;

    float local = -(wbic * (Lb1 + Lb2) + wcon * (Lc1 + Lc2) + wpix * Lp) * ln2;

#pragma unroll
    for (int off = 32; off > 0; off >>= 1)
        local += __shfl_down(local, off, 64);

    __shared__ float wsum[4];
    if (lane == 0) wsum[wid] = local;
    __syncthreads();
    if (tid == 0) {
        atomicAdd(out, wsum[0] + wsum[1] + wsum[2] + wsum[3]);
    }
}

extern "C" void kernel_launch(void* const* d_in, const int* in_sizes, int n_in,
                              void* d_out, int out_size, void* d_ws, size_t ws_size,
                              hipStream_t stream) {
    const float* atts   = (const float*)d_in[0];
    const float* dets   = (const float*)d_in[1];
    const float* target = (const float*)d_in[2];
    const float* con    = (const float*)d_in[3];
    float* out = (float*)d_out;

    hipMemsetAsync(out, 0, sizeof(float), stream);

    const int ngroups = BB * HH * WW / 4;   // 524288 threads, 4 px each
    bicon_loss_kernel<<<ngroups / 256, 256, 0, stream>>>(atts, dets, target, con, out);
}

// Round 2
// 207.669 us; speedup vs baseline: 1.0055x; 1.0055x over previous
//
#include <hip/hip_runtime.h>
#include <stdint.h>

#define BB 8
#define CC 8
#define HH 512
#define WW 512
#define HWSZ (HH * WW)

typedef float v4 __attribute__((ext_vector_type(4)));

#define LOG2_CLAMP -144.26950409f   // -100 / ln2

__device__ __forceinline__ v4 aload4(const float* __restrict__ p) {
    return *(const v4* __restrict__)p;
}
__device__ __forceinline__ v4 lds4(const float* p) {
    return *(const v4*)p;
}

__device__ __forceinline__ v4 sig4(v4 x) {
    v4 r;
#pragma unroll
    for (int i = 0; i < 4; ++i)
        r[i] = __builtin_amdgcn_rcpf(1.0f + __expf(-x[i]));
    return r;
}

// async global->LDS, 16B/lane, dest = wave-uniform base + lane*16 (linear mapping)
__device__ __forceinline__ void gload_lds16(const float* g, float* l) {
    __builtin_amdgcn_global_load_lds(
        (const __attribute__((address_space(1))) void*)g,
        (__attribute__((address_space(3))) void*)l, 16, 0, 0);
}

// Stage one input's tile: center planes sC = [8ch][18 rows][64 cols] floats
// (rows row0-1 .. row0+16, cols col0..col0+63), halo sH = [8ch][2 sides][32] v4
// (side 0: cols col0-4..col0-1, side 1: cols col0+64..col0+67; rows as center).
// All global rows/cols clamped; clamped garbage is only ever consumed under a
// zero border mask. 11 global_load_lds per thread, zero VGPR destinations.
__device__ __forceinline__ void stage_tile(
    const float* __restrict__ ib, float* sC, v4* sH,
    int tid, int row0, int col0)
{
#pragma unroll
    for (int i = 0; i < 9; ++i) {                    // 2304 v4 = 9*256, no tail
        const unsigned j  = (unsigned)(i * 256 + tid);
        const unsigned ch = j / 288u;                // magic-mul
        const unsigned r  = (j - ch * 288u) >> 4;
        const unsigned cv = j & 15u;                 // 16 | 288
        int gr = row0 - 1 + (int)r;
        gr = min(max(gr, 0), HH - 1);
        gload_lds16(ib + ch * HWSZ + gr * WW + col0 + cv * 4, sC + j * 4);
    }
    const int colL = max(col0 - 4, 0);
    const int colR = min(col0 + 64, WW - 4);
#pragma unroll
    for (int l = 0; l < 2; ++l) {                    // halo: [ch][side][r<18]
        const unsigned j    = (unsigned)(l * 256 + tid);
        const unsigned ch   = j >> 6;
        const unsigned side = (j >> 5) & 1u;
        const unsigned r    = j & 31u;
        int gr = row0 - 1 + (int)min(r, 17u);        // valid addr even if masked
        gr = min(max(gr, 0), HH - 1);
        if (r < 18u)
            gload_lds16(ib + ch * HWSZ + gr * WW + (side ? colR : colL),
                        (float*)(sH + j));
    }
}

// One branch from the LDS tile. Produces the probability products (logs done
// by the caller so they can overlap the next staging phase).
template <bool NEED_MIN>
__device__ __forceinline__ void eval_prod(
    const float* sC, const v4* sH, int tx, int ty, uint32_t sel,
    const float* mkA, const float* mkB, const float* mkC,
    v4& pb0o, v4& pb1o, v4& pco, v4& glo, v4& vminO)
{
    const v4 one = {1.f, 1.f, 1.f, 1.f};
    v4 pb0 = one, pb1 = one, pc = one;
    v4 vsum = {0.f, 0.f, 0.f, 0.f};
    v4 vmin = {1e30f, 1e30f, 1e30f, 1e30f};
    const int NCH[8] = {7, 6, 5, 4, 3, 2, 1, 0};     // neighbor channel per vote
    const int DR[8]  = {0, 0, 0, 1, 1, 2, 2, 2};     // LDS row offset (U/C/D)
    const int SS[8]  = {-1, 0, 1, -1, 1, -1, 0, 1};  // col shift
#pragma unroll
    for (int k = 0; k < 8; ++k) {
        v4 s = sig4(lds4(sC + k * 1152 + (ty + 1) * 64 + tx * 4));
        const int ch = NCH[k];
        const float* rowp = sC + ch * 1152 + (ty + DR[k]) * 64;
        v4 qc = lds4(rowp + tx * 4);
        v4 nraw;
        if (SS[k] == 0) {
            nraw = qc;
        } else if (SS[k] < 0) {
            v4 qp = (tx > 0) ? lds4(rowp + tx * 4 - 4)
                             : sH[(ch * 2 + 0) * 32 + (ty + DR[k])];
            nraw = __builtin_shufflevector(qp, qc, 3, 4, 5, 6);
        } else {
            v4 qn = (tx < 15) ? lds4(rowp + tx * 4 + 4)
                              : sH[(ch * 2 + 1) * 32 + (ty + DR[k])];
            nraw = __builtin_shufflevector(qc, qn, 1, 2, 3, 4);
        }
        v4 n = sig4(nraw);
        n[0] *= mkA[k]; n[1] *= mkB[k]; n[2] *= mkB[k]; n[3] *= mkC[k];
        v4 v = s * n;
        vsum += v;
        if (NEED_MIN) vmin = __builtin_elementwise_min(vmin, v);
        v4 av, as;
#pragma unroll
        for (int i = 0; i < 4; ++i) {
            const bool bt = (sel >> (k * 4 + i)) & 1u;
            av[i] = bt ? v[i] : 1.0f - v[i];
            as[i] = bt ? s[i] : 1.0f - s[i];
        }
        if (k < 4) pb0 *= av; else pb1 *= av;
        pc *= as;
    }
    pb0o = pb0; pb1o = pb1; pco = pc;
    glo = vsum * 0.125f;
    if (NEED_MIN) vminO = vmin;
}

__global__ __launch_bounds__(256, 3) void bicon_loss_kernel(
    const float* __restrict__ atts, const float* __restrict__ dets,
    const float* __restrict__ target, const float* __restrict__ con,
    float* __restrict__ out)
{
    // 45 KB shared between the atts phase and the dets phase -> 3 blocks/CU
    __shared__ __align__(16) float sC[8 * 18 * 64];   // 36864 B
    __shared__ __align__(16) v4    sH[512];           // 8192 B ([ch][2][32], r<18 valid)
    __shared__ float wsum[4];

    // XCD-chunked swizzle (2048 % 8 == 0, bijective): vertical-halo neighbor
    // blocks (bid +/- 8) land on the same XCD's L2.
    const int nchunk = (int)gridDim.x >> 3;
    const int bid = ((int)blockIdx.x & 7) * nchunk + ((int)blockIdx.x >> 3);

    const int tid  = (int)threadIdx.x;
    const int colt = bid & 7;            // 8 col-tiles of 64 px
    const int band = (bid >> 3) & 31;    // 32 row-bands of 16 rows
    const int b    = bid >> 8;
    const int row0 = band << 4;
    const int col0 = colt << 6;
    const int tx = tid & 15;             // quad-col within tile
    const int ty = tid >> 4;             // row within tile
    const int h  = row0 + ty;
    const int w0 = col0 + (tx << 2);
    const int lane = tid & 63;
    const int wid  = tid >> 6;

    const float mh0 = (h > 0) ? 1.0f : 0.0f;
    const float mh1 = (h < HH - 1) ? 1.0f : 0.0f;
    const float mw0 = (w0 == 0) ? 0.0f : 1.0f;
    const float mw3 = (w0 == WW - 4) ? 0.0f : 1.0f;

    const float* __restrict__ ab = atts + b * CC * HWSZ;
    const float* __restrict__ db = dets + b * CC * HWSZ;
    const float* __restrict__ cb = con  + b * CC * HWSZ;
    const int offC = h * WW + w0;

    // ---- con/target register loads first (retire before staging: overlap) ----
    v4 cvv[8];
#pragma unroll
    for (int c = 0; c < 8; ++c) cvv[c] = aload4(cb + c * HWSZ + offC);
    v4 tv = aload4(target + b * HWSZ + offC);

    // ---- issue atts staging (11 VGPR-free loads in flight) ----
    stage_tile(ab, sC, sH, tid, row0, col0);

    // ---- selector bitmasks + masks, overlapping the staging flight ----
    uint32_t sel = 0u;
#pragma unroll
    for (int c = 0; c < 8; ++c)
#pragma unroll
        for (int i = 0; i < 4; ++i)
            if (cvv[c][i] > 0.5f) sel |= (1u << (c * 4 + i));
    uint32_t tb = 0u;
#pragma unroll
    for (int i = 0; i < 4; ++i)
        if (tv[i] > 0.5f) tb |= (1u << i);

    const float mkA[8] = {mh0 * mw0, mh0, mh0,       mw0, 1.f, mh1 * mw0, mh1, mh1};
    const float mkB[8] = {mh0,       mh0, mh0,       1.f, 1.f, mh1,       mh1, mh1};
    const float mkC[8] = {mh0,       mh0, mh0 * mw3, 1.f, mw3, mh1,       mh1, mh1 * mw3};

    asm volatile("s_waitcnt vmcnt(0)" ::: "memory");
    __syncthreads();                                  // atts tile visible

    // ================= atts branch (products only) =================
    v4 pb0_1, pb1_1, pc_1, glo1, vdum;
    eval_prod<false>(sC, sH, tx, ty, sel, mkA, mkB, mkC,
                     pb0_1, pb1_1, pc_1, glo1, vdum);

    __syncthreads();                                  // everyone done reading atts
    stage_tile(db, sC, sH, tid, row0, col0);          // issue dets staging ASAP

    // atts logs overlap the dets staging flight (pure VALU)
    float Lb1 = 0.f, Lc1 = 0.f;
#pragma unroll
    for (int i = 0; i < 4; ++i) {
        Lb1 += fmaxf(__log2f(pb0_1[i]), LOG2_CLAMP) + fmaxf(__log2f(pb1_1[i]), LOG2_CLAMP);
        Lc1 += fmaxf(__log2f(pc_1[i]), LOG2_CLAMP);
    }

    asm volatile("s_waitcnt vmcnt(0)" ::: "memory");
    __syncthreads();                                  // dets tile visible

    // ================= dets branch =================
    v4 pb0_2, pb1_2, pc_2, glo2, vmin2;
    eval_prod<true>(sC, sH, tx, ty, sel, mkA, mkB, mkC,
                    pb0_2, pb1_2, pc_2, glo2, vmin2);
    float Lb2 = 0.f, Lc2 = 0.f;
#pragma unroll
    for (int i = 0; i < 4; ++i) {
        Lb2 += fmaxf(__log2f(pb0_2[i]), LOG2_CLAMP) + fmaxf(__log2f(pb1_2[i]), LOG2_CLAMP);
        Lc2 += fmaxf(__log2f(pc_2[i]), LOG2_CLAMP);
    }

    // ============ pixel-level: bce(glo1,t) + bce(dec,t), combined log ============
    float Lp = 0.f;
#pragma unroll
    for (int i = 0; i < 4; ++i) {
        const uint32_t mI    = 0x11111111u << i;
        const uint32_t bitsI = sel & mI;
        const bool edge = (bitsI != 0u) && (bitsI != mI);   // 0 < popcount < 8
        const float dec = edge ? (1.0f - vmin2[i]) : glo2[i];
        const bool  ti  = (tb >> i) & 1u;
        const float a   = ti ? glo1[i] : 1.0f - glo1[i];
        const float bs  = ti ? dec     : 1.0f - dec;
        Lp += fmaxf(__log2f(a * bs), LOG2_CLAMP);
    }

    const float wbic = 0.2f / (float)(BB * CC * HWSZ);
    const float wcon = 0.8f / (float)(BB * CC * HWSZ);
    const float wpix = 1.0f / (float)(BB * HWSZ);
    const float ln2  = 0.69314718056f;

    float local = -(wbic * (Lb1 + Lb2) + wcon * (Lc1 + Lc2) + wpix * Lp) * ln2;

#pragma unroll
    for (int off = 32; off > 0; off >>= 1)
        local += __shfl_down(local, off, 64);

    if (lane == 0) wsum[wid] = local;
    __syncthreads();
    if (tid == 0) {
        atomicAdd(out, wsum[0] + wsum[1] + wsum[2] + wsum[3]);
    }
}

extern "C" void kernel_launch(void* const* d_in, const int* in_sizes, int n_in,
                              void* d_out, int out_size, void* d_ws, size_t ws_size,
                              hipStream_t stream) {
    const float* atts   = (const float*)d_in[0];
    const float* dets   = (const float*)d_in[1];
    const float* target = (const float*)d_in[2];
    const float* con    = (const float*)d_in[3];
    float* out = (float*)d_out;

    hipMemsetAsync(out, 0, sizeof(float), stream);

    const int nblocks = BB * (HH / 16) * (WW / 64);   // 2048 blocks, 16x64 px tiles
    bicon_loss_kernel<<<nblocks, 256, 0, stream>>>(atts, dets, target, con, out);
}